// Round 2
// baseline (175.997 us; speedup 1.0000x reference)
//
#include <hip/hip_runtime.h>

// Problem constants
#define BSZ 128
#define NV 321
#define IN_DIM 336
#define OUT_DIM 96
#define NC 8
#define ROWS (BSZ * NV)   // 41088
#define KSTEPS 11         // ceil(337/32) -> K padded to 352 (bias folded at k=336)
#define NCH (NC * KSTEPS) // 88 chunks of 32-k
#define CHUNK_HALFS 3072  // 96 cols x 32 k
#define CHUNK_BYTES 6144
#define NRING 6

typedef _Float16 half8 __attribute__((ext_vector_type(8)));
typedef float floatx4 __attribute__((ext_vector_type(4)));
typedef float floatx2 __attribute__((ext_vector_type(2)));

// ---------------------------------------------------------------------------
// Kernel 1: reorganize W (8,96,336) f32 + b (8,96) f32 into k-chunk layout:
// w16p[chunk=c*11+ks][o][kk] fp16, chunk contiguous 6144 B, bias at k==336.
// ---------------------------------------------------------------------------
__global__ __launch_bounds__(256) void convert_w_kernel(
    const float* __restrict__ W, const float* __restrict__ b,
    _Float16* __restrict__ w16p) {
  int t = blockIdx.x * 256 + threadIdx.x;
  if (t >= NC * KSTEPS * OUT_DIM * 4) return;  // one half8 per thread
  int kk0 = (t & 3) * 8;
  int o = (t >> 2) % OUT_DIM;
  int chunk = (t >> 2) / OUT_DIM;
  int ks = chunk % KSTEPS;
  int c = chunk / KSTEPS;
  int k0 = ks * 32 + kk0;
  const float* wr = W + (size_t)(c * OUT_DIM + o) * IN_DIM;
  half8 h;
#pragma unroll
  for (int j = 0; j < 8; ++j) {
    int k = k0 + j;
    float v = (k < IN_DIM) ? wr[k] : ((k == IN_DIM) ? b[c * OUT_DIM + o] : 0.0f);
    h[j] = (_Float16)v;
  }
  *(half8*)(w16p + (size_t)chunk * CHUNK_HALFS + o * 32 + kk0) = h;
}

// ---------------------------------------------------------------------------
// helpers
// ---------------------------------------------------------------------------
__device__ __forceinline__ void stage16(const _Float16* g, const _Float16* l) {
  __builtin_amdgcn_global_load_lds(
      (const __attribute__((address_space(1))) void*)g,
      (__attribute__((address_space(3))) void*)l, 16, 0, 0);
}

__device__ __forceinline__ void vm_wait(int n) {  // n is compile-time constant
  if (n <= 0)      asm volatile("s_waitcnt vmcnt(0)" ::: "memory");
  else if (n == 1) asm volatile("s_waitcnt vmcnt(1)" ::: "memory");
  else if (n == 2) asm volatile("s_waitcnt vmcnt(2)" ::: "memory");
  else if (n == 3) asm volatile("s_waitcnt vmcnt(3)" ::: "memory");
  else if (n == 4) asm volatile("s_waitcnt vmcnt(4)" ::: "memory");
  else if (n == 5) asm volatile("s_waitcnt vmcnt(5)" ::: "memory");
  else if (n == 6) asm volatile("s_waitcnt vmcnt(6)" ::: "memory");
  else if (n == 7) asm volatile("s_waitcnt vmcnt(7)" ::: "memory");
  else             asm volatile("s_waitcnt vmcnt(8)" ::: "memory");
}

__device__ __forceinline__ half8 cvt8(floatx4 f0, floatx4 f1) {
  half8 h;
  h[0] = (_Float16)f0[0]; h[1] = (_Float16)f0[1];
  h[2] = (_Float16)f0[2]; h[3] = (_Float16)f0[3];
  h[4] = (_Float16)f1[0]; h[5] = (_Float16)f1[1];
  h[6] = (_Float16)f1[2]; h[7] = (_Float16)f1[3];
  return h;
}

// ---------------------------------------------------------------------------
// Kernel 2: fused cluster GEMM. 64 rows/block, 256 thr = 4 waves (2 wm x 2 wc),
// wave tile 32 rows x 48 cols. A (x, fp16, bias-folded) fully register-resident
// (22 frags = 88 VGPR). B streamed via 6-slot LDS ring, global_load_lds,
// counted vmcnt + raw barriers, ds_reads pipelined one chunk ahead.
// ---------------------------------------------------------------------------
__global__ __launch_bounds__(256, 2) void cluster_gemm_kernel(
    const float* __restrict__ x, const float* __restrict__ prob,
    const _Float16* __restrict__ w16p, float* __restrict__ out) {
  __shared__ __align__(16) _Float16 bb[NRING][CHUNK_HALFS];
  __shared__ float probs[64 * NC];

  const int tid = threadIdx.x;
  const int rbase = blockIdx.x * 64;
  const int lane = tid & 63;
  const int wave = tid >> 6;   // 0..3
  const int wm = wave >> 1;    // 0..1 row half
  const int wc = wave & 1;     // 0..1 col half
  const int l15 = lane & 15;
  const int lg = lane >> 4;    // 0..3

  // ---- prob -> LDS (64 rows x 8 clusters, f32)
  {
    floatx2 v = *(const floatx2*)(prob + (size_t)rbase * NC + tid * 2);
    *(floatx2*)&probs[tid * 2] = v;
  }

  // ---- A tile -> registers (fp16), bias folded at k==336
  half8 a[2][KSTEPS];
#pragma unroll
  for (int m = 0; m < 2; ++m) {
    const float* xr = x + (size_t)(rbase + wm * 32 + m * 16 + l15) * IN_DIM + lg * 8;
#pragma unroll
    for (int ks = 0; ks < 10; ++ks) {
      floatx4 f0 = *(const floatx4*)(xr + ks * 32);
      floatx4 f1 = *(const floatx4*)(xr + ks * 32 + 4);
      a[m][ks] = cvt8(f0, f1);
    }
    if (lg < 2) {  // k = 320 + lg*8 .. +7  (< 336)
      floatx4 f0 = *(const floatx4*)(xr + 320);
      floatx4 f1 = *(const floatx4*)(xr + 320 + 4);
      a[m][10] = cvt8(f0, f1);
    } else {
      half8 z = {};
      if (lg == 2) z[0] = (_Float16)1.0f;  // bias column
      a[m][10] = z;
    }
  }

  // drain ALL global loads so vmcnt counts only ring stages from here on
  asm volatile("s_waitcnt vmcnt(0)" ::: "memory");

  // ---- stage helper geometry: wave segments of the 6144B chunk
  // w0:[0,2048) w1:[2048,4096) w2:[4096,5120) w3:[5120,6144)
  const int seg0 = (wave < 2) ? wave * 2048 : 4096 + (wave - 2) * 1024;
  const int nseg = (wave < 2) ? 2 : 1;
  const int lane16 = lane * 16;

#define STAGE(CH)                                                              \
  do {                                                                         \
    const _Float16* gsrc =                                                     \
        w16p + (size_t)(CH)*CHUNK_HALFS;                                       \
    stage16((const _Float16*)((const char*)gsrc + seg0 + lane16),              \
            (const _Float16*)((const char*)&bb[(CH) % NRING][0] + seg0));      \
    if (nseg == 2)                                                             \
      stage16((const _Float16*)((const char*)gsrc + seg0 + 1024 + lane16),     \
              (const _Float16*)((const char*)&bb[(CH) % NRING][0] + seg0 +     \
                               1024));                                         \
  } while (0)

  // prologue: 5 chunks in flight
  STAGE(0); STAGE(1); STAGE(2); STAGE(3); STAGE(4);

  // chunk 0 ready (allow 4 newer stages = 8 loads for w0/w1, 4 for w2/w3)
  if (wave < 2) vm_wait(8); else vm_wait(4);
  asm volatile("s_waitcnt lgkmcnt(0)" ::: "memory");  // probs ds_write drained
  __builtin_amdgcn_s_barrier();

  // per-slot read base (half index): col = wc*48 + n*16 + l15, k = lg*8
  const int rdoff = (wc * 48 + l15) * 32 + lg * 8;

  // preload chunk 0 fragments
  half8 bcur0 = *(const half8*)(&bb[0][rdoff]);
  half8 bcur1 = *(const half8*)(&bb[0][rdoff + 512]);
  half8 bcur2 = *(const half8*)(&bb[0][rdoff + 1024]);

  floatx4 oacc[2][3] = {};
  floatx4 acc[2][3] = {};

#pragma unroll
  for (int it = 0; it < NCH; ++it) {
    const int c = it / KSTEPS;
    const int ks = it % KSTEPS;

    // wait: chunk it+1 retired; allow min(3, 86-it) newer stages in flight
    {
      int rem = 86 - it; if (rem < 0) rem = 0;
      const int base = rem > 3 ? 3 : rem;
      if (wave < 2) vm_wait(base * 2); else vm_wait(base);
    }
    __builtin_amdgcn_s_barrier();

    // stage chunk it+5 (overwrites slot holding chunk it-1; safe past barrier)
    if (it + 5 < NCH) STAGE(it + 5);

    // pipelined read of chunk it+1 fragments
    half8 bn0, bn1, bn2;
    if (it + 1 < NCH) {
      const _Float16* bp = &bb[(it + 1) % NRING][rdoff];
      bn0 = *(const half8*)(bp);
      bn1 = *(const half8*)(bp + 512);
      bn2 = *(const half8*)(bp + 1024);
    }

    // MFMA on current chunk (A in regs, B in regs from previous iter)
    acc[0][0] = __builtin_amdgcn_mfma_f32_16x16x32_f16(a[0][ks], bcur0, acc[0][0], 0, 0, 0);
    acc[1][0] = __builtin_amdgcn_mfma_f32_16x16x32_f16(a[1][ks], bcur0, acc[1][0], 0, 0, 0);
    acc[0][1] = __builtin_amdgcn_mfma_f32_16x16x32_f16(a[0][ks], bcur1, acc[0][1], 0, 0, 0);
    acc[1][1] = __builtin_amdgcn_mfma_f32_16x16x32_f16(a[1][ks], bcur1, acc[1][1], 0, 0, 0);
    acc[0][2] = __builtin_amdgcn_mfma_f32_16x16x32_f16(a[0][ks], bcur2, acc[0][2], 0, 0, 0);
    acc[1][2] = __builtin_amdgcn_mfma_f32_16x16x32_f16(a[1][ks], bcur2, acc[1][2], 0, 0, 0);

    if (ks == KSTEPS - 1) {  // cluster boundary: prob-weighted accumulate
#pragma unroll
      for (int m = 0; m < 2; ++m) {
#pragma unroll
        for (int r = 0; r < 4; ++r) {
          float p = probs[(wm * 32 + m * 16 + lg * 4 + r) * NC + c];
          oacc[m][0][r] += p * acc[m][0][r];
          oacc[m][1][r] += p * acc[m][1][r];
          oacc[m][2][r] += p * acc[m][2][r];
        }
      }
#pragma unroll
      for (int m = 0; m < 2; ++m) {
        acc[m][0] = (floatx4){0.f, 0.f, 0.f, 0.f};
        acc[m][1] = (floatx4){0.f, 0.f, 0.f, 0.f};
        acc[m][2] = (floatx4){0.f, 0.f, 0.f, 0.f};
      }
    }

    bcur0 = bn0; bcur1 = bn1; bcur2 = bn2;
  }

  // ---- store: D layout col = l15, row = lg*4 + r
#pragma unroll
  for (int m = 0; m < 2; ++m) {
#pragma unroll
    for (int n = 0; n < 3; ++n) {
#pragma unroll
      for (int r = 0; r < 4; ++r) {
        int grow = rbase + wm * 32 + m * 16 + lg * 4 + r;
        out[(size_t)grow * OUT_DIM + wc * 48 + n * 16 + l15] = oacc[m][n][r];
      }
    }
  }
#undef STAGE
}

// ---------------------------------------------------------------------------
extern "C" void kernel_launch(void* const* d_in, const int* in_sizes, int n_in,
                              void* d_out, int out_size, void* d_ws, size_t ws_size,
                              hipStream_t stream) {
  const float* x = (const float*)d_in[0];     // (128,321,336)
  const float* prob = (const float*)d_in[1];  // (128,321,8)
  const float* W = (const float*)d_in[2];     // (8,96,336)
  const float* b = (const float*)d_in[3];     // (8,96)
  float* out = (float*)d_out;                 // (128,321,96)
  _Float16* w16p = (_Float16*)d_ws;           // 88 chunks * 6144 B = 540,672 B

  const int ct = NC * KSTEPS * OUT_DIM * 4;   // one half8 per thread
  hipLaunchKernelGGL(convert_w_kernel, dim3((ct + 255) / 256), dim3(256), 0,
                     stream, W, b, w16p);
  hipLaunchKernelGGL(cluster_gemm_kernel, dim3(ROWS / 64), dim3(256), 0, stream,
                     x, prob, w16p, out);
}

// Round 5
// 147.896 us; speedup vs baseline: 1.1900x; 1.1900x over previous
//
#include <hip/hip_runtime.h>

// Problem constants
#define BSZ 128
#define NV 321
#define IN_DIM 336
#define OUT_DIM 96
#define NC 8
#define ROWS (BSZ * NV)   // 41088
#define KSTEPS 11         // K padded to 352 (bias folded at k=336)
#define NCH (NC * KSTEPS) // 88 chunks of 32-k
#define CHUNK_HALFS 3072  // 4 kgroups x 96 cols x 8 halfs
#define CHUNK_BYTES 6144
#define NRING 8           // ring slots (power of 2 -> &7)

typedef _Float16 half8 __attribute__((ext_vector_type(8)));
typedef float floatx4 __attribute__((ext_vector_type(4)));
typedef float floatx2 __attribute__((ext_vector_type(2)));

// ---------------------------------------------------------------------------
// Kernel 1: W (8,96,336) f32 + b (8,96) f32 -> chunked fp16 layout:
// w16p[chunk = c*11+ks][kgroup = kk/8][o][kk%8], bias folded at k==336.
// A 16-lane ds_read_b128 group then reads 256 contiguous bytes (2-way, free).
// ---------------------------------------------------------------------------
__global__ __launch_bounds__(256) void convert_w_kernel(
    const float* __restrict__ W, const float* __restrict__ b,
    _Float16* __restrict__ w16p) {
  int t = blockIdx.x * 256 + threadIdx.x;
  if (t >= NCH * OUT_DIM * 4) return;  // one half8 per thread
  int lg = t & 3;             // kgroup
  int o = (t >> 2) % OUT_DIM;
  int chunk = (t >> 2) / OUT_DIM;
  int ks = chunk % KSTEPS;
  int c = chunk / KSTEPS;
  int k0 = ks * 32 + lg * 8;
  const float* wr = W + (size_t)(c * OUT_DIM + o) * IN_DIM;
  half8 h;
#pragma unroll
  for (int j = 0; j < 8; ++j) {
    int k = k0 + j;
    float v = (k < IN_DIM) ? wr[k] : ((k == IN_DIM) ? b[c * OUT_DIM + o] : 0.0f);
    h[j] = (_Float16)v;
  }
  *(half8*)(w16p + (size_t)chunk * CHUNK_HALFS + lg * 768 + o * 8) = h;
}

// ---------------------------------------------------------------------------
// helpers
// ---------------------------------------------------------------------------
__device__ __forceinline__ void stage16(const _Float16* g, const _Float16* l) {
  __builtin_amdgcn_global_load_lds(
      (const __attribute__((address_space(1))) void*)g,
      (__attribute__((address_space(3))) void*)l, 16, 0, 0);
}

__device__ __forceinline__ half8 cvt8(floatx4 f0, floatx4 f1) {
  half8 h;
  h[0] = (_Float16)f0[0]; h[1] = (_Float16)f0[1];
  h[2] = (_Float16)f0[2]; h[3] = (_Float16)f0[3];
  h[4] = (_Float16)f1[0]; h[5] = (_Float16)f1[1];
  h[6] = (_Float16)f1[2]; h[7] = (_Float16)f1[3];
  return h;
}

// ---------------------------------------------------------------------------
// Kernel 2: fused cluster GEMM. 64 rows/block, 4 waves (2 wm x 2 wc),
// wave tile 32 rows x 48 cols. A (x, fp16, bias folded) register-resident,
// STATICALLY indexed (outer c-loop runtime, inner ks fully unrolled).
// B streamed via 8-slot LDS ring (global_load_lds, counted vmcnt, one
// barrier/chunk, ds_reads pipelined one chunk ahead).
// ---------------------------------------------------------------------------
__global__ __launch_bounds__(256, 2) void cluster_gemm_kernel(
    const float* __restrict__ x, const float* __restrict__ prob,
    const _Float16* __restrict__ w16p, float* __restrict__ out) {
  __shared__ __align__(16) _Float16 bb[NRING][CHUNK_HALFS];
  __shared__ float probs[64 * NC];

  const int tid = threadIdx.x;
  const int rbase = blockIdx.x * 64;
  const int lane = tid & 63;
  const int wave = tid >> 6;   // 0..3
  const int wm = wave >> 1;    // row half
  const int wc = wave & 1;     // col half
  const int l15 = lane & 15;
  const int lg = lane >> 4;    // 0..3

  // ---- prob -> LDS (64 rows x 8 clusters f32)
  {
    floatx2 v = *(const floatx2*)(prob + (size_t)rbase * NC + tid * 2);
    *(floatx2*)&probs[tid * 2] = v;
  }

  // ---- A tile -> registers (fp16), bias folded at k==336
  half8 a[2][KSTEPS];
#pragma unroll
  for (int m = 0; m < 2; ++m) {
    const float* xr = x + (size_t)(rbase + wm * 32 + m * 16 + l15) * IN_DIM + lg * 8;
#pragma unroll
    for (int ks = 0; ks < 10; ++ks) {
      floatx4 f0 = *(const floatx4*)(xr + ks * 32);
      floatx4 f1 = *(const floatx4*)(xr + ks * 32 + 4);
      a[m][ks] = cvt8(f0, f1);
    }
    if (lg < 2) {  // k = 320 + lg*8 + j  (< 336)
      floatx4 f0 = *(const floatx4*)(xr + 320);
      floatx4 f1 = *(const floatx4*)(xr + 320 + 4);
      a[m][10] = cvt8(f0, f1);
    } else {
      half8 z = {};
      if (lg == 2) z[0] = (_Float16)1.0f;  // bias column
      a[m][10] = z;
    }
  }

  // drain all global loads so vmcnt counts only ring stages from here on
  asm volatile("s_waitcnt vmcnt(0)" ::: "memory");

  // ---- stage geometry: w0:[0,2048) w1:[2048,4096) w2:[4096,5120) w3:[5120,6144)
  const int seg0 = (wave < 2) ? wave * 2048 : 4096 + (wave - 2) * 1024;
  const int nseg = (wave < 2) ? 2 : 1;
  const int lane16 = lane * 16;

#define STAGE(CH)                                                              \
  do {                                                                         \
    const char* gsrc = (const char*)(w16p + (size_t)(CH) * CHUNK_HALFS);       \
    char* ldst = (char*)&bb[(CH) & (NRING - 1)][0];                            \
    stage16((const _Float16*)(gsrc + seg0 + lane16),                           \
            (const _Float16*)(ldst + seg0));                                   \
    if (nseg == 2)                                                             \
      stage16((const _Float16*)(gsrc + seg0 + 1024 + lane16),                  \
              (const _Float16*)(ldst + seg0 + 1024));                          \
  } while (0)

  // prologue: chunks 0..6 in flight
  STAGE(0); STAGE(1); STAGE(2); STAGE(3); STAGE(4); STAGE(5); STAGE(6);

  // chunk 0 ready: allow 6 newer chunks outstanding
  if (wave < 2) asm volatile("s_waitcnt vmcnt(12)" ::: "memory");
  else          asm volatile("s_waitcnt vmcnt(6)" ::: "memory");
  asm volatile("s_waitcnt lgkmcnt(0)" ::: "memory");  // probs visible
  __builtin_amdgcn_s_barrier();

  // B read base (halfs): [lg][o][8]; o = wc*48 + n*16 + l15
  const int rdoff = lg * 768 + (wc * 48 + l15) * 8;

  half8 bcur0 = *(const half8*)(&bb[0][rdoff]);
  half8 bcur1 = *(const half8*)(&bb[0][rdoff + 128]);
  half8 bcur2 = *(const half8*)(&bb[0][rdoff + 256]);

  floatx4 oacc[2][3] = {};
  floatx4 acc[2][3] = {};

  for (int c = 0; c < NC; ++c) {
#pragma unroll
    for (int ks = 0; ks < KSTEPS; ++ks) {
      const int it = c * KSTEPS + ks;

      // ensure chunk it+1 landed (own segments); allow 5 newer chunks
      if (wave < 2) asm volatile("s_waitcnt vmcnt(10)" ::: "memory");
      else          asm volatile("s_waitcnt vmcnt(5)" ::: "memory");
      __builtin_amdgcn_s_barrier();  // cross-wave: it+1 fully resident

      // stage chunk it+7 into slot that held chunk it-1 (all waves past it)
      if (it + 7 < NCH) STAGE(it + 7);

      // pipelined read of chunk it+1 fragments
      half8 bn0 = {}, bn1 = {}, bn2 = {};
      if (it + 1 < NCH) {
        const _Float16* bp = &bb[(it + 1) & (NRING - 1)][rdoff];
        bn0 = *(const half8*)(bp);
        bn1 = *(const half8*)(bp + 128);
        bn2 = *(const half8*)(bp + 256);
      }

      acc[0][0] = __builtin_amdgcn_mfma_f32_16x16x32_f16(a[0][ks], bcur0, acc[0][0], 0, 0, 0);
      acc[1][0] = __builtin_amdgcn_mfma_f32_16x16x32_f16(a[1][ks], bcur0, acc[1][0], 0, 0, 0);
      acc[0][1] = __builtin_amdgcn_mfma_f32_16x16x32_f16(a[0][ks], bcur1, acc[0][1], 0, 0, 0);
      acc[1][1] = __builtin_amdgcn_mfma_f32_16x16x32_f16(a[1][ks], bcur1, acc[1][1], 0, 0, 0);
      acc[0][2] = __builtin_amdgcn_mfma_f32_16x16x32_f16(a[0][ks], bcur2, acc[0][2], 0, 0, 0);
      acc[1][2] = __builtin_amdgcn_mfma_f32_16x16x32_f16(a[1][ks], bcur2, acc[1][2], 0, 0, 0);

      if (ks == KSTEPS - 1) {  // cluster boundary: prob-weighted accumulate
#pragma unroll
        for (int m = 0; m < 2; ++m) {
#pragma unroll
          for (int r = 0; r < 4; ++r) {
            float p = probs[(wm * 32 + m * 16 + lg * 4 + r) * NC + c];
            oacc[m][0][r] += p * acc[m][0][r];
            oacc[m][1][r] += p * acc[m][1][r];
            oacc[m][2][r] += p * acc[m][2][r];
          }
          acc[m][0] = (floatx4){0.f, 0.f, 0.f, 0.f};
          acc[m][1] = (floatx4){0.f, 0.f, 0.f, 0.f};
          acc[m][2] = (floatx4){0.f, 0.f, 0.f, 0.f};
        }
      }

      bcur0 = bn0; bcur1 = bn1; bcur2 = bn2;
    }
  }

  // ---- store: D layout col = l15, row = lg*4 + r
#pragma unroll
  for (int m = 0; m < 2; ++m) {
#pragma unroll
    for (int n = 0; n < 3; ++n) {
#pragma unroll
      for (int r = 0; r < 4; ++r) {
        int grow = rbase + wm * 32 + m * 16 + lg * 4 + r;
        out[(size_t)grow * OUT_DIM + wc * 48 + n * 16 + l15] = oacc[m][n][r];
      }
    }
  }
#undef STAGE
}

// ---------------------------------------------------------------------------
extern "C" void kernel_launch(void* const* d_in, const int* in_sizes, int n_in,
                              void* d_out, int out_size, void* d_ws, size_t ws_size,
                              hipStream_t stream) {
  const float* x = (const float*)d_in[0];     // (128,321,336)
  const float* prob = (const float*)d_in[1];  // (128,321,8)
  const float* W = (const float*)d_in[2];     // (8,96,336)
  const float* b = (const float*)d_in[3];     // (8,96)
  float* out = (float*)d_out;                 // (128,321,96)
  _Float16* w16p = (_Float16*)d_ws;           // 88 chunks * 6144 B = 540,672 B

  const int ct = NCH * OUT_DIM * 4;           // one half8 per thread
  hipLaunchKernelGGL(convert_w_kernel, dim3((ct + 255) / 256), dim3(256), 0,
                     stream, W, b, w16p);
  hipLaunchKernelGGL(cluster_gemm_kernel, dim3(ROWS / 64), dim3(256), 0, stream,
                     x, prob, w16p, out);
}